// Round 1
// baseline (2579.540 us; speedup 1.0000x reference)
//
#include <hip/hip_runtime.h>
#include <cstddef>

// Problem constants (match reference)
constexpr int NN = 20000;    // nodes
constexpr int NE = 320000;   // edges
constexpr int NQ = 100000;   // queries
constexpr int DD = 256;      // feature dim

// ---------------------------------------------------------------------------
// Degree histogram: deg[row[e]] += 1
__global__ __launch_bounds__(256) void k_deg(const int* __restrict__ row,
                                             float* __restrict__ deg) {
    int e = blockIdx.x * 256 + threadIdx.x;
    if (e < NE) atomicAdd(&deg[row[e]], 1.0f);
}

// recip[i] = 1 / max(deg[i], 1)
__global__ __launch_bounds__(256) void k_recip(const float* __restrict__ deg,
                                               float* __restrict__ recip) {
    int i = blockIdx.x * 256 + threadIdx.x;
    if (i < NN) recip[i] = 1.0f / fmaxf(deg[i], 1.0f);
}

// ---------------------------------------------------------------------------
// Scatter: agg[row[e], :] += x[col[e], :]   (one wave per edge, float4/lane)
__global__ __launch_bounds__(256) void k_scatter(const int* __restrict__ row,
                                                 const int* __restrict__ col,
                                                 const float* __restrict__ x,
                                                 float* __restrict__ agg) {
    int idx = blockIdx.x * 256 + threadIdx.x;
    int e = idx >> 6;
    int lane = idx & 63;
    if (e >= NE) return;
    int r = row[e];
    int c = col[e];
    float4 v = *reinterpret_cast<const float4*>(x + (size_t)c * DD + lane * 4);
    float* dst = agg + (size_t)r * DD + lane * 4;
    atomicAdd(dst + 0, v.x);
    atomicAdd(dst + 1, v.y);
    atomicAdd(dst + 2, v.z);
    atomicAdd(dst + 3, v.w);
}

// ---------------------------------------------------------------------------
// Fused SAGE layer: out = [relu]( (agg*recip) @ Wl + b + x @ Wr )
// Block: 256 threads, 32 rows x 256 cols tile. Thread: 8 rows x 4 cols.
// out may alias agg (block reads its own rows into LDS before writing).
template <int RELU>
__global__ __launch_bounds__(256) void k_sage(const float* __restrict__ agg,
                                              const float* __restrict__ recip,
                                              const float* __restrict__ x,
                                              const float* __restrict__ Wl,
                                              const float* __restrict__ b,
                                              const float* __restrict__ Wr,
                                              float* __restrict__ out) {
    __shared__ float sa[32][DD];
    __shared__ float sx[32][DD];
    const int tid = threadIdx.x;
    const int r0 = blockIdx.x * 32;

    for (int s = 0; s < 32; ++s) {
        int r = r0 + s;
        float rc = recip[r];
        sa[s][tid] = agg[(size_t)r * DD + tid] * rc;
        sx[s][tid] = x[(size_t)r * DD + tid];
    }
    __syncthreads();

    const int j0 = (tid & 63) * 4;      // 64 col groups x 4 cols
    const int rg = (tid >> 6) * 8;      // 4 row groups x 8 rows

    float acc[8][4];
#pragma unroll
    for (int s = 0; s < 8; ++s)
#pragma unroll
        for (int c = 0; c < 4; ++c) acc[s][c] = 0.0f;

    for (int k = 0; k < DD; k += 4) {
        float wl[4][4], wr[4][4];
#pragma unroll
        for (int kk = 0; kk < 4; ++kk) {
            float4 t = *reinterpret_cast<const float4*>(Wl + (size_t)(k + kk) * DD + j0);
            wl[kk][0] = t.x; wl[kk][1] = t.y; wl[kk][2] = t.z; wl[kk][3] = t.w;
            float4 u = *reinterpret_cast<const float4*>(Wr + (size_t)(k + kk) * DD + j0);
            wr[kk][0] = u.x; wr[kk][1] = u.y; wr[kk][2] = u.z; wr[kk][3] = u.w;
        }
#pragma unroll
        for (int s = 0; s < 8; ++s) {
            float4 a4 = *reinterpret_cast<const float4*>(&sa[rg + s][k]);
            float4 b4 = *reinterpret_cast<const float4*>(&sx[rg + s][k]);
            float av[4] = {a4.x, a4.y, a4.z, a4.w};
            float bv[4] = {b4.x, b4.y, b4.z, b4.w};
#pragma unroll
            for (int kk = 0; kk < 4; ++kk)
#pragma unroll
                for (int c = 0; c < 4; ++c)
                    acc[s][c] += av[kk] * wl[kk][c] + bv[kk] * wr[kk][c];
        }
    }

    float4 bb = *reinterpret_cast<const float4*>(b + j0);
    float bvv[4] = {bb.x, bb.y, bb.z, bb.w};
#pragma unroll
    for (int s = 0; s < 8; ++s) {
        float4 o;
        float ov[4];
#pragma unroll
        for (int c = 0; c < 4; ++c) {
            float v = acc[s][c] + bvv[c];
            if (RELU) v = fmaxf(v, 0.0f);
            ov[c] = v;
        }
        o.x = ov[0]; o.y = ov[1]; o.z = ov[2]; o.w = ov[3];
        *reinterpret_cast<float4*>(out + (size_t)(r0 + rg + s) * DD + j0) = o;
    }
}

// ---------------------------------------------------------------------------
// Predictor: h = x2[e0]*x2[e1]; h2 = relu(h @ Wp1 + bp1); out = sigmoid(h2 . Wp2 + bp2)
__global__ __launch_bounds__(256) void k_pred(const int* __restrict__ edges,
                                              const float* __restrict__ x2,
                                              const float* __restrict__ Wp1,
                                              const float* __restrict__ bp1,
                                              const float* __restrict__ Wp2,
                                              const float* __restrict__ bp2,
                                              float* __restrict__ out) {
    __shared__ float sh[32][DD];
    const int tid = threadIdx.x;
    const int q0 = blockIdx.x * 32;

    for (int s = 0; s < 32; ++s) {
        int q = q0 + s;
        int a = edges[q];
        int c = edges[NQ + q];
        sh[s][tid] = x2[(size_t)a * DD + tid] * x2[(size_t)c * DD + tid];
    }
    __syncthreads();

    const int j0 = (tid & 63) * 4;
    const int rg = (tid >> 6) * 8;

    float acc[8][4];
#pragma unroll
    for (int s = 0; s < 8; ++s)
#pragma unroll
        for (int c = 0; c < 4; ++c) acc[s][c] = 0.0f;

    for (int k = 0; k < DD; k += 4) {
        float w[4][4];
#pragma unroll
        for (int kk = 0; kk < 4; ++kk) {
            float4 t = *reinterpret_cast<const float4*>(Wp1 + (size_t)(k + kk) * DD + j0);
            w[kk][0] = t.x; w[kk][1] = t.y; w[kk][2] = t.z; w[kk][3] = t.w;
        }
#pragma unroll
        for (int s = 0; s < 8; ++s) {
            float4 a4 = *reinterpret_cast<const float4*>(&sh[rg + s][k]);
            float av[4] = {a4.x, a4.y, a4.z, a4.w};
#pragma unroll
            for (int kk = 0; kk < 4; ++kk)
#pragma unroll
                for (int c = 0; c < 4; ++c) acc[s][c] += av[kk] * w[kk][c];
        }
    }

    float4 bb = *reinterpret_cast<const float4*>(bp1 + j0);
    float bvv[4] = {bb.x, bb.y, bb.z, bb.w};
    __syncthreads();   // all reads of sh done
#pragma unroll
    for (int s = 0; s < 8; ++s)
#pragma unroll
        for (int c = 0; c < 4; ++c)
            sh[rg + s][j0 + c] = fmaxf(acc[s][c] + bvv[c], 0.0f);
    __syncthreads();

    // Final dot: 8 threads per row, rotated k to avoid bank conflicts
    int rowi = tid >> 3;
    int oct = tid & 7;
    int rot = tid & 31;
    float partial = 0.0f;
#pragma unroll
    for (int i = 0; i < 32; ++i) {
        int kk = oct * 32 + ((i + rot) & 31);
        partial += sh[rowi][kk] * Wp2[kk];
    }
    partial += __shfl_down(partial, 4);
    partial += __shfl_down(partial, 2);
    partial += __shfl_down(partial, 1);
    if (oct == 0) {
        float z = partial + bp2[0];
        out[q0 + rowi] = 1.0f / (1.0f + expf(-z));
    }
}

// ---------------------------------------------------------------------------
extern "C" void kernel_launch(void* const* d_in, const int* in_sizes, int n_in,
                              void* d_out, int out_size, void* d_ws, size_t ws_size,
                              hipStream_t stream) {
    const int*   adj_row = (const int*)d_in[0];
    const int*   adj_col = (const int*)d_in[1];
    const int*   edges   = (const int*)d_in[2];
    const float* emb     = (const float*)d_in[3];
    const float* W1l     = (const float*)d_in[4];
    const float* b1      = (const float*)d_in[5];
    const float* W1r     = (const float*)d_in[6];
    const float* W2l     = (const float*)d_in[7];
    const float* b2      = (const float*)d_in[8];
    const float* W2r     = (const float*)d_in[9];
    const float* Wp1     = (const float*)d_in[10];
    const float* bp1     = (const float*)d_in[11];
    const float* Wp2     = (const float*)d_in[12];
    const float* bp2     = (const float*)d_in[13];
    float* out = (float*)d_out;

    // Workspace layout (bytes)
    char* ws = (char*)d_ws;
    float* agg   = (float*)(ws);                               // NN*DD*4 = 20.48 MB
    float* x1    = (float*)(ws + (size_t)NN * DD * 4);         // NN*DD*4
    float* deg   = (float*)(ws + (size_t)2 * NN * DD * 4);     // NN*4
    float* recip = (float*)(ws + (size_t)2 * NN * DD * 4 + NN * 4);
    float* x2    = agg;  // layer-2 output aliases agg (safe: per-block rows)

    const size_t aggBytes = (size_t)NN * DD * 4;

    // Degree (shared by both layers)
    hipMemsetAsync(deg, 0, NN * 4, stream);
    k_deg<<<(NE + 255) / 256, 256, 0, stream>>>(adj_row, deg);
    k_recip<<<(NN + 255) / 256, 256, 0, stream>>>(deg, recip);

    // Layer 1
    hipMemsetAsync(agg, 0, aggBytes, stream);
    k_scatter<<<(NE * 64) / 256, 256, 0, stream>>>(adj_row, adj_col, emb, agg);
    k_sage<1><<<NN / 32, 256, 0, stream>>>(agg, recip, emb, W1l, b1, W1r, x1);

    // Layer 2 (output aliases agg)
    hipMemsetAsync(agg, 0, aggBytes, stream);
    k_scatter<<<(NE * 64) / 256, 256, 0, stream>>>(adj_row, adj_col, x1, agg);
    k_sage<0><<<NN / 32, 256, 0, stream>>>(agg, recip, x1, W2l, b2, W2r, x2);

    // Predictor
    k_pred<<<NQ / 32, 256, 0, stream>>>(edges, x2, Wp1, bp1, Wp2, bp2, out);
}

// Round 2
// 552.224 us; speedup vs baseline: 4.6712x; 4.6712x over previous
//
#include <hip/hip_runtime.h>
#include <cstddef>

// Problem constants (match reference)
constexpr int NN = 20000;    // nodes
constexpr int NE = 320000;   // edges
constexpr int NQ = 100000;   // queries
constexpr int DD = 256;      // feature dim

// ---------------------------------------------------------------------------
// Degree histogram (int): deg[row[e]] += 1
__global__ __launch_bounds__(256) void k_deg(const int* __restrict__ row,
                                             int* __restrict__ deg) {
    int e = blockIdx.x * 256 + threadIdx.x;
    if (e < NE) atomicAdd(&deg[e < NE ? row[e] : 0], 1);
}

// Single-block exclusive scan over deg -> offs[NN+1], cursor copy, recip.
__global__ __launch_bounds__(256) void k_scan(const int* __restrict__ deg,
                                              int* __restrict__ offs,
                                              int* __restrict__ cursor,
                                              float* __restrict__ recip) {
    __shared__ int wsum[4];
    __shared__ int s_carry;
    const int tid = threadIdx.x;
    const int wid = tid >> 6;
    const int lane = tid & 63;
    if (tid == 0) s_carry = 0;
    __syncthreads();
    for (int base = 0; base < NN; base += 256) {
        int i = base + tid;
        int v = (i < NN) ? deg[i] : 0;
        int sc = v;
#pragma unroll
        for (int d = 1; d < 64; d <<= 1) {
            int t = __shfl_up(sc, d);
            if (lane >= d) sc += t;
        }
        if (lane == 63) wsum[wid] = sc;
        __syncthreads();
        int wpre = 0;
        for (int w = 0; w < wid; ++w) wpre += wsum[w];
        int carry = s_carry;
        int incl = carry + wpre + sc;
        if (i < NN) {
            offs[i] = incl - v;
            cursor[i] = incl - v;
            recip[i] = 1.0f / fmaxf((float)v, 1.0f);
        }
        __syncthreads();
        if (tid == 255) s_carry = incl;
        __syncthreads();
    }
    if (tid == 0) offs[NN] = s_carry;
}

// Fill CSR adjacency: scol[cursor[row[e]]++] = col[e]
__global__ __launch_bounds__(256) void k_fill(const int* __restrict__ row,
                                              const int* __restrict__ col,
                                              int* __restrict__ cursor,
                                              int* __restrict__ scol) {
    int e = blockIdx.x * 256 + threadIdx.x;
    if (e < NE) {
        int r = row[e];
        int p = atomicAdd(&cursor[r], 1);
        scol[p] = col[e];
    }
}

// ---------------------------------------------------------------------------
// Gather-aggregate (mean): agg[i,:] = recip[i] * sum_{c in N(i)} x[c,:]
// One wave (64 lanes, float4) per node; 4 nodes per block.
__global__ __launch_bounds__(256) void k_agg(const int* __restrict__ offs,
                                             const int* __restrict__ scol,
                                             const float* __restrict__ recip,
                                             const float* __restrict__ x,
                                             float* __restrict__ agg) {
    int node = blockIdx.x * 4 + (threadIdx.x >> 6);
    int lane = threadIdx.x & 63;
    if (node >= NN) return;
    int s = offs[node];
    int e = offs[node + 1];
    float4 acc0 = {0, 0, 0, 0};
    float4 acc1 = {0, 0, 0, 0};
    int p = s;
    for (; p + 1 < e; p += 2) {
        int c0 = scol[p];
        int c1 = scol[p + 1];
        float4 v0 = *reinterpret_cast<const float4*>(x + (size_t)c0 * DD + lane * 4);
        float4 v1 = *reinterpret_cast<const float4*>(x + (size_t)c1 * DD + lane * 4);
        acc0.x += v0.x; acc0.y += v0.y; acc0.z += v0.z; acc0.w += v0.w;
        acc1.x += v1.x; acc1.y += v1.y; acc1.z += v1.z; acc1.w += v1.w;
    }
    if (p < e) {
        int c0 = scol[p];
        float4 v0 = *reinterpret_cast<const float4*>(x + (size_t)c0 * DD + lane * 4);
        acc0.x += v0.x; acc0.y += v0.y; acc0.z += v0.z; acc0.w += v0.w;
    }
    float rc = recip[node];
    float4 o;
    o.x = (acc0.x + acc1.x) * rc;
    o.y = (acc0.y + acc1.y) * rc;
    o.z = (acc0.z + acc1.z) * rc;
    o.w = (acc0.w + acc1.w) * rc;
    *reinterpret_cast<float4*>(agg + (size_t)node * DD + lane * 4) = o;
}

// ---------------------------------------------------------------------------
// Fused SAGE layer: out = [relu]( agg @ Wl + b + x @ Wr )   (agg pre-normalized)
// Block: 256 threads, 32 rows x 256 cols tile. Thread: 8 rows x 4 cols.
// out may alias agg (block reads its own rows into LDS before writing).
template <int RELU>
__global__ __launch_bounds__(256) void k_sage(const float* __restrict__ agg,
                                              const float* __restrict__ x,
                                              const float* __restrict__ Wl,
                                              const float* __restrict__ b,
                                              const float* __restrict__ Wr,
                                              float* __restrict__ out) {
    __shared__ float sa[32][DD];
    __shared__ float sx[32][DD];
    const int tid = threadIdx.x;
    const int r0 = blockIdx.x * 32;

    for (int s = 0; s < 32; ++s) {
        int r = r0 + s;
        sa[s][tid] = agg[(size_t)r * DD + tid];
        sx[s][tid] = x[(size_t)r * DD + tid];
    }
    __syncthreads();

    const int j0 = (tid & 63) * 4;      // 64 col groups x 4 cols
    const int rg = (tid >> 6) * 8;      // 4 row groups x 8 rows

    float acc[8][4];
#pragma unroll
    for (int s = 0; s < 8; ++s)
#pragma unroll
        for (int c = 0; c < 4; ++c) acc[s][c] = 0.0f;

    for (int k = 0; k < DD; k += 4) {
        float wl[4][4], wr[4][4];
#pragma unroll
        for (int kk = 0; kk < 4; ++kk) {
            float4 t = *reinterpret_cast<const float4*>(Wl + (size_t)(k + kk) * DD + j0);
            wl[kk][0] = t.x; wl[kk][1] = t.y; wl[kk][2] = t.z; wl[kk][3] = t.w;
            float4 u = *reinterpret_cast<const float4*>(Wr + (size_t)(k + kk) * DD + j0);
            wr[kk][0] = u.x; wr[kk][1] = u.y; wr[kk][2] = u.z; wr[kk][3] = u.w;
        }
#pragma unroll
        for (int s = 0; s < 8; ++s) {
            float4 a4 = *reinterpret_cast<const float4*>(&sa[rg + s][k]);
            float4 b4 = *reinterpret_cast<const float4*>(&sx[rg + s][k]);
            float av[4] = {a4.x, a4.y, a4.z, a4.w};
            float bv[4] = {b4.x, b4.y, b4.z, b4.w};
#pragma unroll
            for (int kk = 0; kk < 4; ++kk)
#pragma unroll
                for (int c = 0; c < 4; ++c)
                    acc[s][c] += av[kk] * wl[kk][c] + bv[kk] * wr[kk][c];
        }
    }

    float4 bb = *reinterpret_cast<const float4*>(b + j0);
    float bvv[4] = {bb.x, bb.y, bb.z, bb.w};
#pragma unroll
    for (int s = 0; s < 8; ++s) {
        float4 o;
        float ov[4];
#pragma unroll
        for (int c = 0; c < 4; ++c) {
            float v = acc[s][c] + bvv[c];
            if (RELU) v = fmaxf(v, 0.0f);
            ov[c] = v;
        }
        o.x = ov[0]; o.y = ov[1]; o.z = ov[2]; o.w = ov[3];
        *reinterpret_cast<float4*>(out + (size_t)(r0 + rg + s) * DD + j0) = o;
    }
}

// ---------------------------------------------------------------------------
// Predictor: h = x2[e0]*x2[e1]; h2 = relu(h @ Wp1 + bp1); out = sigmoid(h2 . Wp2 + bp2)
__global__ __launch_bounds__(256) void k_pred(const int* __restrict__ edges,
                                              const float* __restrict__ x2,
                                              const float* __restrict__ Wp1,
                                              const float* __restrict__ bp1,
                                              const float* __restrict__ Wp2,
                                              const float* __restrict__ bp2,
                                              float* __restrict__ out) {
    __shared__ float sh[32][DD];
    const int tid = threadIdx.x;
    const int q0 = blockIdx.x * 32;

    for (int s = 0; s < 32; ++s) {
        int q = q0 + s;
        int a = edges[q];
        int c = edges[NQ + q];
        sh[s][tid] = x2[(size_t)a * DD + tid] * x2[(size_t)c * DD + tid];
    }
    __syncthreads();

    const int j0 = (tid & 63) * 4;
    const int rg = (tid >> 6) * 8;

    float acc[8][4];
#pragma unroll
    for (int s = 0; s < 8; ++s)
#pragma unroll
        for (int c = 0; c < 4; ++c) acc[s][c] = 0.0f;

    for (int k = 0; k < DD; k += 4) {
        float w[4][4];
#pragma unroll
        for (int kk = 0; kk < 4; ++kk) {
            float4 t = *reinterpret_cast<const float4*>(Wp1 + (size_t)(k + kk) * DD + j0);
            w[kk][0] = t.x; w[kk][1] = t.y; w[kk][2] = t.z; w[kk][3] = t.w;
        }
#pragma unroll
        for (int s = 0; s < 8; ++s) {
            float4 a4 = *reinterpret_cast<const float4*>(&sh[rg + s][k]);
            float av[4] = {a4.x, a4.y, a4.z, a4.w};
#pragma unroll
            for (int kk = 0; kk < 4; ++kk)
#pragma unroll
                for (int c = 0; c < 4; ++c) acc[s][c] += av[kk] * w[kk][c];
        }
    }

    float4 bb = *reinterpret_cast<const float4*>(bp1 + j0);
    float bvv[4] = {bb.x, bb.y, bb.z, bb.w};
    __syncthreads();   // all reads of sh done
#pragma unroll
    for (int s = 0; s < 8; ++s)
#pragma unroll
        for (int c = 0; c < 4; ++c)
            sh[rg + s][j0 + c] = fmaxf(acc[s][c] + bvv[c], 0.0f);
    __syncthreads();

    // Final dot: 8 threads per row, rotated k to avoid bank conflicts
    int rowi = tid >> 3;
    int oct = tid & 7;
    int rot = tid & 31;
    float partial = 0.0f;
#pragma unroll
    for (int i = 0; i < 32; ++i) {
        int kk = oct * 32 + ((i + rot) & 31);
        partial += sh[rowi][kk] * Wp2[kk];
    }
    partial += __shfl_down(partial, 4);
    partial += __shfl_down(partial, 2);
    partial += __shfl_down(partial, 1);
    if (oct == 0) {
        float z = partial + bp2[0];
        out[q0 + rowi] = 1.0f / (1.0f + expf(-z));
    }
}

// ---------------------------------------------------------------------------
extern "C" void kernel_launch(void* const* d_in, const int* in_sizes, int n_in,
                              void* d_out, int out_size, void* d_ws, size_t ws_size,
                              hipStream_t stream) {
    const int*   adj_row = (const int*)d_in[0];
    const int*   adj_col = (const int*)d_in[1];
    const int*   edges   = (const int*)d_in[2];
    const float* emb     = (const float*)d_in[3];
    const float* W1l     = (const float*)d_in[4];
    const float* b1      = (const float*)d_in[5];
    const float* W1r     = (const float*)d_in[6];
    const float* W2l     = (const float*)d_in[7];
    const float* b2      = (const float*)d_in[8];
    const float* W2r     = (const float*)d_in[9];
    const float* Wp1     = (const float*)d_in[10];
    const float* bp1     = (const float*)d_in[11];
    const float* Wp2     = (const float*)d_in[12];
    const float* bp2     = (const float*)d_in[13];
    float* out = (float*)d_out;

    // Workspace layout
    char* ws = (char*)d_ws;
    size_t off = 0;
    float* agg    = (float*)(ws + off); off += (size_t)NN * DD * 4;   // 20.48 MB
    float* x1     = (float*)(ws + off); off += (size_t)NN * DD * 4;   // 20.48 MB
    int*   deg    = (int*)(ws + off);   off += (size_t)NN * 4;
    int*   offs   = (int*)(ws + off);   off += (size_t)(NN + 1) * 4;
    int*   cursor = (int*)(ws + off);   off += (size_t)NN * 4;
    float* recip  = (float*)(ws + off); off += (size_t)NN * 4;
    int*   scol   = (int*)(ws + off);   off += (size_t)NE * 4;        // 1.28 MB
    float* x2 = agg;  // layer-2 output aliases agg (safe: per-block rows)

    // Build CSR (shared by both layers)
    hipMemsetAsync(deg, 0, NN * 4, stream);
    k_deg<<<(NE + 255) / 256, 256, 0, stream>>>(adj_row, deg);
    k_scan<<<1, 256, 0, stream>>>(deg, offs, cursor, recip);
    k_fill<<<(NE + 255) / 256, 256, 0, stream>>>(adj_row, adj_col, cursor, scol);

    // Layer 1
    k_agg<<<(NN + 3) / 4, 256, 0, stream>>>(offs, scol, recip, emb, agg);
    k_sage<1><<<NN / 32, 256, 0, stream>>>(agg, emb, W1l, b1, W1r, x1);

    // Layer 2 (output aliases agg)
    k_agg<<<(NN + 3) / 4, 256, 0, stream>>>(offs, scol, recip, x1, agg);
    k_sage<0><<<NN / 32, 256, 0, stream>>>(agg, x1, W2l, b2, W2r, x2);

    // Predictor
    k_pred<<<NQ / 32, 256, 0, stream>>>(edges, x2, Wp1, bp1, Wp2, bp2, out);
}

// Round 3
// 479.667 us; speedup vs baseline: 5.3778x; 1.1513x over previous
//
#include <hip/hip_runtime.h>
#include <cstddef>

// Problem constants (match reference)
constexpr int NN = 20000;    // nodes
constexpr int NE = 320000;   // edges
constexpr int NQ = 100000;   // queries
constexpr int DD = 256;      // feature dim

typedef __attribute__((ext_vector_type(8))) short bf16x8;
typedef __attribute__((ext_vector_type(4))) float f32x4;
typedef __attribute__((ext_vector_type(4))) unsigned short u16x4;

__device__ inline unsigned short f2bf(float f) {
    union { float f; unsigned u; } v; v.f = f;
    unsigned r = v.u + 0x7fffu + ((v.u >> 16) & 1u);   // RNE
    return (unsigned short)(r >> 16);
}

// ---------------------------------------------------------------------------
// Degree histogram (int): deg[row[e]] += 1
__global__ __launch_bounds__(256) void k_deg(const int* __restrict__ row,
                                             int* __restrict__ deg) {
    int e = blockIdx.x * 256 + threadIdx.x;
    if (e < NE) atomicAdd(&deg[row[e]], 1);
}

// Single-block exclusive scan over deg -> offs[NN+1], cursor copy, recip.
__global__ __launch_bounds__(256) void k_scan(const int* __restrict__ deg,
                                              int* __restrict__ offs,
                                              int* __restrict__ cursor,
                                              float* __restrict__ recip) {
    __shared__ int wsum[4];
    __shared__ int s_carry;
    const int tid = threadIdx.x;
    const int wid = tid >> 6;
    const int lane = tid & 63;
    if (tid == 0) s_carry = 0;
    __syncthreads();
    for (int base = 0; base < NN; base += 256) {
        int i = base + tid;
        int v = (i < NN) ? deg[i] : 0;
        int sc = v;
#pragma unroll
        for (int d = 1; d < 64; d <<= 1) {
            int t = __shfl_up(sc, d);
            if (lane >= d) sc += t;
        }
        if (lane == 63) wsum[wid] = sc;
        __syncthreads();
        int wpre = 0;
        for (int w = 0; w < wid; ++w) wpre += wsum[w];
        int carry = s_carry;
        int incl = carry + wpre + sc;
        if (i < NN) {
            offs[i] = incl - v;
            cursor[i] = incl - v;
            recip[i] = 1.0f / fmaxf((float)v, 1.0f);
        }
        __syncthreads();
        if (tid == 255) s_carry = incl;
        __syncthreads();
    }
    if (tid == 0) offs[NN] = s_carry;
}

// Fill CSR adjacency: scol[cursor[row[e]]++] = col[e]
__global__ __launch_bounds__(256) void k_fill(const int* __restrict__ row,
                                              const int* __restrict__ col,
                                              int* __restrict__ cursor,
                                              int* __restrict__ scol) {
    int e = blockIdx.x * 256 + threadIdx.x;
    if (e < NE) {
        int r = row[e];
        int p = atomicAdd(&cursor[r], 1);
        scol[p] = col[e];
    }
}

// ---------------------------------------------------------------------------
// Gather-aggregate (mean): agg[i,:] = recip[i] * sum_{c in N(i)} x[c,:]
__global__ __launch_bounds__(256) void k_agg(const int* __restrict__ offs,
                                             const int* __restrict__ scol,
                                             const float* __restrict__ recip,
                                             const float* __restrict__ x,
                                             float* __restrict__ agg) {
    int node = blockIdx.x * 4 + (threadIdx.x >> 6);
    int lane = threadIdx.x & 63;
    if (node >= NN) return;
    int s = offs[node];
    int e = offs[node + 1];
    float4 acc0 = {0, 0, 0, 0};
    float4 acc1 = {0, 0, 0, 0};
    int p = s;
    for (; p + 1 < e; p += 2) {
        int c0 = scol[p];
        int c1 = scol[p + 1];
        float4 v0 = *reinterpret_cast<const float4*>(x + (size_t)c0 * DD + lane * 4);
        float4 v1 = *reinterpret_cast<const float4*>(x + (size_t)c1 * DD + lane * 4);
        acc0.x += v0.x; acc0.y += v0.y; acc0.z += v0.z; acc0.w += v0.w;
        acc1.x += v1.x; acc1.y += v1.y; acc1.z += v1.z; acc1.w += v1.w;
    }
    if (p < e) {
        int c0 = scol[p];
        float4 v0 = *reinterpret_cast<const float4*>(x + (size_t)c0 * DD + lane * 4);
        acc0.x += v0.x; acc0.y += v0.y; acc0.z += v0.z; acc0.w += v0.w;
    }
    float rc = recip[node];
    float4 o;
    o.x = (acc0.x + acc1.x) * rc;
    o.y = (acc0.y + acc1.y) * rc;
    o.z = (acc0.z + acc1.z) * rc;
    o.w = (acc0.w + acc1.w) * rc;
    *reinterpret_cast<float4*>(agg + (size_t)node * DD + lane * 4) = o;
}

// ---------------------------------------------------------------------------
// Fused SAGE layer (fp32 exact): out = [relu]( agg @ Wl + b + x @ Wr )
template <int RELU>
__global__ __launch_bounds__(256) void k_sage(const float* __restrict__ agg,
                                              const float* __restrict__ x,
                                              const float* __restrict__ Wl,
                                              const float* __restrict__ b,
                                              const float* __restrict__ Wr,
                                              float* __restrict__ out) {
    __shared__ float sa[32][DD];
    __shared__ float sx[32][DD];
    const int tid = threadIdx.x;
    const int r0 = blockIdx.x * 32;

    for (int s = 0; s < 32; ++s) {
        int r = r0 + s;
        sa[s][tid] = agg[(size_t)r * DD + tid];
        sx[s][tid] = x[(size_t)r * DD + tid];
    }
    __syncthreads();

    const int j0 = (tid & 63) * 4;
    const int rg = (tid >> 6) * 8;

    float acc[8][4];
#pragma unroll
    for (int s = 0; s < 8; ++s)
#pragma unroll
        for (int c = 0; c < 4; ++c) acc[s][c] = 0.0f;

    for (int k = 0; k < DD; k += 4) {
        float wl[4][4], wr[4][4];
#pragma unroll
        for (int kk = 0; kk < 4; ++kk) {
            float4 t = *reinterpret_cast<const float4*>(Wl + (size_t)(k + kk) * DD + j0);
            wl[kk][0] = t.x; wl[kk][1] = t.y; wl[kk][2] = t.z; wl[kk][3] = t.w;
            float4 u = *reinterpret_cast<const float4*>(Wr + (size_t)(k + kk) * DD + j0);
            wr[kk][0] = u.x; wr[kk][1] = u.y; wr[kk][2] = u.z; wr[kk][3] = u.w;
        }
#pragma unroll
        for (int s = 0; s < 8; ++s) {
            float4 a4 = *reinterpret_cast<const float4*>(&sa[rg + s][k]);
            float4 b4 = *reinterpret_cast<const float4*>(&sx[rg + s][k]);
            float av[4] = {a4.x, a4.y, a4.z, a4.w};
            float bv[4] = {b4.x, b4.y, b4.z, b4.w};
#pragma unroll
            for (int kk = 0; kk < 4; ++kk)
#pragma unroll
                for (int c = 0; c < 4; ++c)
                    acc[s][c] += av[kk] * wl[kk][c] + bv[kk] * wr[kk][c];
        }
    }

    float4 bb = *reinterpret_cast<const float4*>(b + j0);
    float bvv[4] = {bb.x, bb.y, bb.z, bb.w};
#pragma unroll
    for (int s = 0; s < 8; ++s) {
        float4 o;
        float ov[4];
#pragma unroll
        for (int c = 0; c < 4; ++c) {
            float v = acc[s][c] + bvv[c];
            if (RELU) v = fmaxf(v, 0.0f);
            ov[c] = v;
        }
        o.x = ov[0]; o.y = ov[1]; o.z = ov[2]; o.w = ov[3];
        *reinterpret_cast<float4*>(out + (size_t)(r0 + rg + s) * DD + j0) = o;
    }
}

// ---------------------------------------------------------------------------
// Pack Wp1 [256][256] fp32 into bf16 MFMA B-fragment layout:
// tile t = kt*16+nt (kt:0..7 K-tiles of 32, nt:0..15 N-tiles of 16).
// P[(t*64+lane)*8 + i] = bf16( Wp1[kt*32+(lane>>4)*8+i][nt*16+(lane&15)] ).
__global__ __launch_bounds__(256) void k_pack(const float* __restrict__ W,
                                              unsigned short* __restrict__ P) {
    int idx = blockIdx.x * 256 + threadIdx.x;   // 0..8191
    if (idx >= 128 * 64) return;
    int t = idx >> 6, lane = idx & 63;
    int kt = t >> 4, nt = t & 15;
    int k0 = kt * 32 + (lane >> 4) * 8;
    int n = nt * 16 + (lane & 15);
    unsigned w[4];
#pragma unroll
    for (int i = 0; i < 4; ++i) {
        unsigned lo = f2bf(W[(size_t)(k0 + 2 * i) * DD + n]);
        unsigned hi = f2bf(W[(size_t)(k0 + 2 * i + 1) * DD + n]);
        w[i] = lo | (hi << 16);
    }
    *reinterpret_cast<uint4*>(P + ((size_t)idx) * 8) =
        make_uint4(w[0], w[1], w[2], w[3]);
}

// ---------------------------------------------------------------------------
// Predictor with bf16 MFMA GEMM, fp32 accumulate.
// Block: 256 threads = 4 waves, 64 queries (16 rows/wave).
__global__ __launch_bounds__(256) void k_pred(const int* __restrict__ edges,
                                              const float* __restrict__ x2,
                                              const unsigned short* __restrict__ Wp1p,
                                              const float* __restrict__ bp1,
                                              const float* __restrict__ Wp2,
                                              const float* __restrict__ bp2,
                                              float* __restrict__ out) {
    __shared__ unsigned short sh[64][264];   // bf16 h tile, padded stride
    const int tid = threadIdx.x;
    const int wave = tid >> 6;
    const int lane = tid & 63;
    const int q0 = blockIdx.x * 64;

    // Gather + multiply + bf16-pack into LDS. Wave w fills rows w*16..w*16+15.
    for (int s = 0; s < 16; ++s) {
        int r = wave * 16 + s;
        int q = q0 + r;
        float4 pa = {0, 0, 0, 0}, pb = {0, 0, 0, 0};
        if (q < NQ) {
            int a = edges[q];
            int c = edges[NQ + q];
            pa = *reinterpret_cast<const float4*>(x2 + (size_t)a * DD + lane * 4);
            pb = *reinterpret_cast<const float4*>(x2 + (size_t)c * DD + lane * 4);
        }
        u16x4 pk;
        pk[0] = f2bf(pa.x * pb.x);
        pk[1] = f2bf(pa.y * pb.y);
        pk[2] = f2bf(pa.z * pb.z);
        pk[3] = f2bf(pa.w * pb.w);
        *reinterpret_cast<u16x4*>(&sh[r][lane * 4]) = pk;
    }
    __syncthreads();

    // GEMM1: rows wave*16..+15 (A) x packed Wp1 (B) -> acc[16] (256 cols)
    f32x4 acc[16];
#pragma unroll
    for (int nt = 0; nt < 16; ++nt) acc[nt] = {0, 0, 0, 0};

    const int arow = wave * 16 + (lane & 15);
    const int akoff = (lane >> 4) * 8;
    for (int kt = 0; kt < 8; ++kt) {
        bf16x8 afrag = *reinterpret_cast<const bf16x8*>(&sh[arow][kt * 32 + akoff]);
#pragma unroll
        for (int nt = 0; nt < 16; ++nt) {
            bf16x8 bfrag = *reinterpret_cast<const bf16x8*>(
                Wp1p + ((size_t)((kt * 16 + nt) * 64 + lane)) * 8);
            acc[nt] = __builtin_amdgcn_mfma_f32_16x16x32_bf16(afrag, bfrag, acc[nt], 0, 0, 0);
        }
    }

    // Epilogue: bias + relu + dot(Wp2) + sigmoid.
    // acc[nt][j] is h2[row=(lane>>4)*4+j][col=nt*16+(lane&15)] (within wave tile)
    float rowsum[4] = {0, 0, 0, 0};
#pragma unroll
    for (int nt = 0; nt < 16; ++nt) {
        int n = nt * 16 + (lane & 15);
        float bias = bp1[n];
        float w2 = Wp2[n];
#pragma unroll
        for (int j = 0; j < 4; ++j) {
            float v = fmaxf(acc[nt][j] + bias, 0.0f);
            rowsum[j] += v * w2;
        }
    }
#pragma unroll
    for (int m = 1; m < 16; m <<= 1) {
#pragma unroll
        for (int j = 0; j < 4; ++j) rowsum[j] += __shfl_xor(rowsum[j], m);
    }
    if ((lane & 15) == 0) {
        float b2v = bp2[0];
#pragma unroll
        for (int j = 0; j < 4; ++j) {
            int q = q0 + wave * 16 + (lane >> 4) * 4 + j;
            if (q < NQ) {
                float z = rowsum[j] + b2v;
                out[q] = 1.0f / (1.0f + expf(-z));
            }
        }
    }
}

// ---------------------------------------------------------------------------
extern "C" void kernel_launch(void* const* d_in, const int* in_sizes, int n_in,
                              void* d_out, int out_size, void* d_ws, size_t ws_size,
                              hipStream_t stream) {
    const int*   adj_row = (const int*)d_in[0];
    const int*   adj_col = (const int*)d_in[1];
    const int*   edges   = (const int*)d_in[2];
    const float* emb     = (const float*)d_in[3];
    const float* W1l     = (const float*)d_in[4];
    const float* b1      = (const float*)d_in[5];
    const float* W1r     = (const float*)d_in[6];
    const float* W2l     = (const float*)d_in[7];
    const float* b2      = (const float*)d_in[8];
    const float* W2r     = (const float*)d_in[9];
    const float* Wp1     = (const float*)d_in[10];
    const float* bp1     = (const float*)d_in[11];
    const float* Wp2     = (const float*)d_in[12];
    const float* bp2     = (const float*)d_in[13];
    float* out = (float*)d_out;

    // Workspace layout
    char* ws = (char*)d_ws;
    size_t off = 0;
    float* agg    = (float*)(ws + off); off += (size_t)NN * DD * 4;   // 20.48 MB
    float* x1     = (float*)(ws + off); off += (size_t)NN * DD * 4;   // 20.48 MB
    int*   deg    = (int*)(ws + off);   off += (size_t)NN * 4;
    int*   offs   = (int*)(ws + off);   off += (size_t)(NN + 1) * 4;
    int*   cursor = (int*)(ws + off);   off += (size_t)NN * 4;
    float* recip  = (float*)(ws + off); off += (size_t)NN * 4;
    int*   scol   = (int*)(ws + off);   off += (size_t)NE * 4;        // 1.28 MB
    unsigned short* Wp1p = (unsigned short*)(ws + off); off += (size_t)DD * DD * 2; // 128 KB
    float* x2 = agg;  // layer-2 output aliases agg (safe: per-block rows)

    // Build CSR (shared by both layers) + pack Wp1 (independent)
    hipMemsetAsync(deg, 0, NN * 4, stream);
    k_deg<<<(NE + 255) / 256, 256, 0, stream>>>(adj_row, deg);
    k_scan<<<1, 256, 0, stream>>>(deg, offs, cursor, recip);
    k_fill<<<(NE + 255) / 256, 256, 0, stream>>>(adj_row, adj_col, cursor, scol);
    k_pack<<<32, 256, 0, stream>>>(Wp1, Wp1p);

    // Layer 1
    k_agg<<<(NN + 3) / 4, 256, 0, stream>>>(offs, scol, recip, emb, agg);
    k_sage<1><<<NN / 32, 256, 0, stream>>>(agg, emb, W1l, b1, W1r, x1);

    // Layer 2 (output aliases agg)
    k_agg<<<(NN + 3) / 4, 256, 0, stream>>>(offs, scol, recip, x1, agg);
    k_sage<0><<<NN / 32, 256, 0, stream>>>(agg, x1, W2l, b2, W2r, x2);

    // Predictor (bf16 MFMA)
    k_pred<<<(NQ + 63) / 64, 256, 0, stream>>>(edges, x2, Wp1p, bp1, Wp2, bp2, out);
}